// Round 7
// baseline (401.765 us; speedup 1.0000x reference)
//
#include <hip/hip_runtime.h>
#include <math.h>

#define B_ROWS 262144
#define MAIN_BLOCKS 1536      // 6 blocks/CU resident, 192 per XCD
#define N_STREAMS (MAIN_BLOCKS * 4)   // 6144 wave streams, 5-6 tiles each
#define TILE_ROWS 8
#define N_TILES 32768         // 262144 / 8
#define TILE_F4 198           // 8*99/4 float4 per array per tile

// ws uint-cell layout:
//  [0..9]    atomicMax of ~map(x) -> global per-feature MIN   (memset 0)
//  [10..19]  atomicMax of  map(x) -> global per-feature MAX   (memset 0)
//  [20] cm, [21] cf  sex counts (atomicAdd)                   (memset 0)
//  [22] ready-counter (prep minmax), [23] done-counter (main) (memset 0)
//  [24..223] hist 100 male + 100 female (int atomicAdd)       (memset 0)
//  [256..]   C partials: 3 x MAIN_BLOCKS floats (fully overwritten)
#define WS_HIST 24
#define WS_C 256
#define WS_ZERO_CELLS 224

__device__ __forceinline__ unsigned int map_f(float x) {
  unsigned int b = __float_as_uint(x);
  return (b & 0x80000000u) ? ~b : (b | 0x80000000u);
}
__device__ __forceinline__ float unmap_f(unsigned int u) {
  unsigned int b = (u & 0x80000000u) ? (u ^ 0x80000000u) : ~u;
  return __uint_as_float(b);
}
__device__ __forceinline__ unsigned int aload(const unsigned int* p) {
  return __hip_atomic_load(p, __ATOMIC_RELAXED, __HIP_MEMORY_SCOPE_AGENT);
}
__device__ __forceinline__ float aloadf(const float* p) {
  return __hip_atomic_load(p, __ATOMIC_RELAXED, __HIP_MEMORY_SCOPE_AGENT);
}

// ============ prep: minmax + gate + histogram in one 128-block kernel ========
// 128 blocks << resident capacity -> all co-resident; the spin-gate runs with
// nothing else on the GPU (the r1-r3 failure was 128 pollers fencing against
// 1408 concurrent streaming blocks). Second enc pass is L2-hot.
__global__ __launch_bounds__(256) void k_prep(const float* __restrict__ enc,
                                              unsigned int* __restrict__ ws) {
  __shared__ float smn[4][10], smx[4][10];
  __shared__ unsigned int sc[4][2];
  __shared__ float mnv[10], wid[10];
  __shared__ unsigned int h[200];
  int tid = threadIdx.x, bid = blockIdx.x;
  int wave = tid >> 6, lane = tid & 63;
  const float4* e4 = (const float4*)enc;

  // ---- phase 1: per-block minmax + sex counts (r0-proven body) ----
  float mn[10], mx[10];
  #pragma unroll
  for (int j = 0; j < 10; j++) { mn[j] = 1e30f; mx[j] = -1e30f; }
  unsigned int cm = 0, cf = 0;
  #pragma unroll
  for (int i = 0; i < 8; i++) {
    size_t g = (size_t)bid * 2048 + i * 256 + tid;
    float4 a = e4[g * 3 + 0], b = e4[g * 3 + 1], c = e4[g * 3 + 2];
    float v[12] = {a.x,a.y,a.z,a.w,b.x,b.y,b.z,b.w,c.x,c.y,c.z,c.w};
    #pragma unroll
    for (int j = 0; j < 10; j++) { mn[j] = fminf(mn[j], v[j]); mx[j] = fmaxf(mx[j], v[j]); }
    cm += (v[11] == 0.0f); cf += (v[11] == 1.0f);
  }
  #pragma unroll
  for (int off = 32; off; off >>= 1) {
    #pragma unroll
    for (int j = 0; j < 10; j++) {
      mn[j] = fminf(mn[j], __shfl_xor(mn[j], off));
      mx[j] = fmaxf(mx[j], __shfl_xor(mx[j], off));
    }
    cm += __shfl_xor(cm, off); cf += __shfl_xor(cf, off);
  }
  if (lane == 0) {
    #pragma unroll
    for (int j = 0; j < 10; j++) { smn[wave][j] = mn[j]; smx[wave][j] = mx[j]; }
    sc[wave][0] = cm; sc[wave][1] = cf;
  }
  __syncthreads();
  if (tid < 10) {
    float m = fminf(fminf(smn[0][tid], smn[1][tid]), fminf(smn[2][tid], smn[3][tid]));
    atomicMax(ws + tid, ~map_f(m));          // min via max of ~map, init 0 (r1-proven)
  } else if (tid < 20) {
    int j = tid - 10;
    float m = fmaxf(fmaxf(smx[0][j], smx[1][j]), fmaxf(smx[2][j], smx[3][j]));
    atomicMax(ws + tid, map_f(m));
  } else if (tid < 22) {
    int j = tid - 20;
    atomicAdd(ws + 20 + j, sc[0][j] + sc[1][j] + sc[2][j] + sc[3][j]);
  }
  __syncthreads();                           // block's global atomics issued
  // ---- gate: all 128 blocks co-resident; spin is brief and uncontended ----
  if (tid == 0) {
    __threadfence();
    __hip_atomic_fetch_add(ws + 22, 1u, __ATOMIC_ACQ_REL, __HIP_MEMORY_SCOPE_AGENT);
    while (__hip_atomic_load(ws + 22, __ATOMIC_ACQUIRE, __HIP_MEMORY_SCOPE_AGENT) < 128u)
      __builtin_amdgcn_s_sleep(2);
  }
  __syncthreads();
  // ---- phase 2: histogram with global min/max (enc L2-hot) ----
  if (tid < 10) {
    unsigned int nm = aload(ws + tid);
    unsigned int xm = aload(ws + 10 + tid);
    float mn_ = unmap_f(~nm);
    mnv[tid] = mn_;
    wid[tid] = fmaxf(unmap_f(xm) - mn_, 1e-12f);
  }
  for (int i = tid; i < 200; i += 256) h[i] = 0u;
  __syncthreads();
  #pragma unroll
  for (int i = 0; i < 8; i++) {
    size_t g = (size_t)bid * 2048 + i * 256 + tid;
    float4 a = e4[g * 3 + 0], b = e4[g * 3 + 1], c = e4[g * 3 + 2];
    float v[12] = {a.x,a.y,a.z,a.w,b.x,b.y,b.z,b.w,c.x,c.y,c.z,c.w};
    int base = (v[11] == 0.0f) ? 0 : ((v[11] == 1.0f) ? 100 : -1);
    if (base >= 0) {
      #pragma unroll
      for (int cc = 0; cc < 10; cc++) {
        float t = (v[cc] - mnv[cc]) / wid[cc] * 10.0f;  // reference op order
        int bi = min(max((int)floorf(t), 0), 9);
        atomicAdd(&h[base + cc * 10 + bi], 1u);
      }
    }
  }
  __syncthreads();
  if (tid < 200) atomicAdd(ws + WS_HIST + tid, h[tid]);  // integer: deterministic
}

// ================= main: r0-exact loop + r5 sweep/LSE + XCD swizzle ==========
__device__ __forceinline__ void issue_d(const float* __restrict__ d,
                                        int tile, int lane, float* bd) {
  const float4* dsp = (const float4*)d + (size_t)tile * TILE_F4;
  #pragma unroll
  for (int it = 0; it < 3; ++it)
    __builtin_amdgcn_global_load_lds(
        (const __attribute__((address_space(1))) void*)(dsp + it * 64 + lane),
        (__attribute__((address_space(3))) void*)(bd + it * 256), 16, 0, 0);
  if (lane < 6)
    __builtin_amdgcn_global_load_lds(
        (const __attribute__((address_space(1))) void*)(dsp + 192 + lane),
        (__attribute__((address_space(3))) void*)(bd + 768), 16, 0, 0);
}

// mse/dot sweep; all-64-lane exp computed in the same pass, stored in place
// (r5-validated, absmax 0). t comes from 4 float4 regs loaded THIS iteration
// (no cross-iteration carries -> no spill; r0-proven).
__device__ __forceinline__ void sweep_tile(float* bd, float4 t0, float4 t1,
                                           float4 t2, float4 t3, int lane,
                                           float& mse, float& dot) {
  float4* b4 = (float4*)bd;
  float4 tvv[4] = {t0, t1, t2, t3};
  #pragma unroll
  for (int it = 0; it < 4; ++it) {
    int f = it * 64 + lane;
    if (it < 3 || lane < 6) {
      float4 xd = b4[f];
      float4 xt = tvv[it];
      int e = f * 4;
      int c = e - (e / 99) * 99;             // magic-mul const divisor
      float dv[4] = {xd.x, xd.y, xd.z, xd.w};
      float tw[4] = {xt.x, xt.y, xt.z, xt.w};
      #pragma unroll
      for (int k = 0; k < 4; k++) {
        int cc = c + k;
        if (cc >= 99) cc -= 99;
        bool cont = (cc == 0) | ((unsigned)(cc - 55) <= 2u);
        float diff = dv[k] - tw[k];
        if (cont) mse += diff * diff;
        else      dot += tw[k] * dv[k];
      }
      float4 ev;
      ev.x = __expf(xd.x); ev.y = __expf(xd.y);
      ev.z = __expf(xd.z); ev.w = __expf(xd.w);
      b4[f] = ev;
    }
  }
}

// LSE over precomputed exp: 2 lanes/row; pure LDS reads + adds + 8 logs.
__device__ __forceinline__ void lse_adds(const float* bd, int lane, float& ce) {
  if (lane < 2 * TILE_ROWS) {
    const float* row = bd + (lane >> 1) * 99;
    float Z;
    if ((lane & 1) == 0) {                // blocks (1,8)(8,24)(24,31)(31,45)(45,51)
      Z = 0.f;
      #pragma unroll
      for (int c = 1; c < 8; c++) Z += row[c];
      ce += __logf(Z);
      Z = 0.f;
      #pragma unroll
      for (int c = 8; c < 24; c++) Z += row[c];
      ce += __logf(Z);
      Z = 0.f;
      #pragma unroll
      for (int c = 24; c < 31; c++) Z += row[c];
      ce += __logf(Z);
      Z = 0.f;
      #pragma unroll
      for (int c = 31; c < 45; c++) Z += row[c];
      ce += __logf(Z);
      Z = 0.f;
      #pragma unroll
      for (int c = 45; c < 51; c++) Z += row[c];
      ce += __logf(Z);
    } else {                              // blocks (51,53)(53,55)(58,99)
      Z = 0.f;
      #pragma unroll
      for (int c = 51; c < 53; c++) Z += row[c];
      ce += __logf(Z);
      Z = 0.f;
      #pragma unroll
      for (int c = 53; c < 55; c++) Z += row[c];
      ce += __logf(Z);
      float Za = 0.f, Zb = 0.f;           // split 41-chain into 2 accumulators
      #pragma unroll
      for (int c = 58; c < 78; c++) Za += row[c];
      #pragma unroll
      for (int c = 78; c < 99; c++) Zb += row[c];
      ce += __logf(Za + Zb);
    }
  }
}

__global__ __launch_bounds__(256, 6) void k_main(const float* __restrict__ d,
                                                 const float* __restrict__ t,
                                                 unsigned int* __restrict__ ws,
                                                 float* __restrict__ out) {
  __shared__ float sd[4][800];          // per-wave d tile (12.8 KB)
  __shared__ float red[12];
  __shared__ float fpart[256];
  __shared__ float fred[16];
  __shared__ int lastflag;
  int tid = threadIdx.x, bid = blockIdx.x;
  int wave = tid >> 6, lane = tid & 63;
  float* ldsd = sd[wave];

  // XCD-contiguous swizzle: HW round-robins bid%8 across XCDs; remap so XCD x
  // owns logical blocks [192x,192x+192) -> each XCD streams a contiguous
  // 2.4 MB window per phase instead of 8-way-shredded 12.6 KB chunks.
  int lbid = ((bid & 7) * (MAIN_BLOCKS / 8)) + (bid >> 3);   // bijective
  int gw = lbid * 4 + wave;             // global wave stream id

  float mse = 0.f, dot = 0.f, ce = 0.f;

  for (int tile = gw; tile < N_TILES; tile += N_STREAMS) {
    issue_d(d, tile, lane, ldsd);                      // 4 DMA in flight
    const float4* tsp = (const float4*)t + (size_t)tile * TILE_F4;
    float4 t0 = tsp[lane];                             // + 4 reg loads
    float4 t1 = tsp[64 + lane];
    float4 t2 = tsp[128 + lane];
    float4 t3 = tsp[192 + ((lane < 6) ? lane : 0)];    // clamped; unused lanes
    // single per-wave drain: covers the DMAs (FIFO) and the t loads (r0-exact)
    asm volatile("s_waitcnt vmcnt(0)" ::: "memory");
    sweep_tile(ldsd, t0, t1, t2, t3, lane, mse, dot);
    asm volatile("s_waitcnt lgkmcnt(0)" ::: "memory"); // exp writes visible
    lse_adds(ldsd, lane, ce);
    // ce-use forces lgkm waits on lse reads before next iter's DMA issues
  }

  // ---- block reduction (single barrier AFTER the streaming loop) ----
  #pragma unroll
  for (int off = 32; off; off >>= 1) {
    mse += __shfl_xor(mse, off);
    dot += __shfl_xor(dot, off);
    ce  += __shfl_xor(ce,  off);
  }
  if (lane == 0) { red[wave] = mse; red[4 + wave] = dot; red[8 + wave] = ce; }
  __syncthreads();
  if (tid == 0) {
    float* C = (float*)(ws + WS_C);
    C[lbid]                   = red[0] + red[1] + red[2]  + red[3];
    C[MAIN_BLOCKS + lbid]     = red[4] + red[5] + red[6]  + red[7];
    C[2 * MAIN_BLOCKS + lbid] = red[8] + red[9] + red[10] + red[11];
  }

  // ---- done-counter election: NO spinning; non-last blocks simply exit ----
  __syncthreads();
  if (tid == 0) {
    __threadfence();
    unsigned int old = __hip_atomic_fetch_add(ws + 23, 1u, __ATOMIC_ACQ_REL,
                                              __HIP_MEMORY_SCOPE_AGENT);
    lastflag = (old == (unsigned int)(MAIN_BLOCKS - 1)) ? 1 : 0;
  }
  __syncthreads();
  if (lastflag == 0) return;
  __threadfence();

  // ---- finalize (runs in the one surviving block) ----
  const float* C = (const float*)(ws + WS_C);
  float msum = 0.f, dsum = 0.f, csum = 0.f;
  for (int i = tid; i < MAIN_BLOCKS; i += 256) {
    msum += aloadf(C + i);
    dsum += aloadf(C + MAIN_BLOCKS + i);
    csum += aloadf(C + 2 * MAIN_BLOCKS + i);
  }
  float term = 0.f;
  if (tid < 100) {
    float cmf = fmaxf((float)aload(ws + 20), 1.0f);
    float cff = fmaxf((float)aload(ws + 21), 1.0f);
    float mc = (float)aload(ws + WS_HIST + tid);
    float fc = (float)aload(ws + WS_HIST + 100 + tid);
    if (mc > 0.f && fc > 0.f) {
      float pp = mc / cmf, qq = fc / cff;
      term = pp * logf(pp / qq);
    }
  }
  #pragma unroll
  for (int off = 32; off; off >>= 1) {
    msum += __shfl_xor(msum, off);
    dsum += __shfl_xor(dsum, off);
    csum += __shfl_xor(csum, off);
    term += __shfl_xor(term, off);
  }
  if (lane == 0) {
    fred[wave] = msum; fred[4 + wave] = dsum; fred[8 + wave] = csum;
    fred[12 + wave] = term;
  }
  __syncthreads();
  if (tid == 0) {
    const float invB = 1.0f / (float)B_ROWS;
    float mse_ = (fred[0] + fred[1] + fred[2] + fred[3]) * invB;
    float dd   = fred[4] + fred[5] + fred[6] + fred[7];
    float cc   = fred[8] + fred[9] + fred[10] + fred[11];
    float ce_  = (cc - dd) * invB;
    float akld = 0.5f * (fred[12] + fred[13] + fred[14] + fred[15]);
    out[0] = 0.5f * (mse_ + ce_) + akld;
    out[1] = mse_;
    out[2] = ce_;
    out[3] = akld;
  }
  (void)fpart;
}

extern "C" void kernel_launch(void* const* d_in, const int* in_sizes, int n_in,
                              void* d_out, int out_size, void* d_ws, size_t ws_size,
                              hipStream_t stream) {
  const float* enc = (const float*)d_in[0];   // data_encoded (B,12)
  const float* dec = (const float*)d_in[1];   // data_decoded (B,99)
  const float* tru = (const float*)d_in[2];   // data_true    (B,99)
  unsigned int* ws = (unsigned int*)d_ws;
  float* out = (float*)d_out;

  hipMemsetAsync(d_ws, 0, WS_ZERO_CELLS * sizeof(unsigned int), stream);
  hipLaunchKernelGGL(k_prep, dim3(128),         dim3(256), 0, stream, enc, ws);
  hipLaunchKernelGGL(k_main, dim3(MAIN_BLOCKS), dim3(256), 0, stream,
                     dec, tru, ws, out);
}

// Round 8
// 266.755 us; speedup vs baseline: 1.5061x; 1.5061x over previous
//
#include <hip/hip_runtime.h>
#include <math.h>

#define B_ROWS 262144

// ws layout (4-byte cells), total 33024 cells = 132 KB (proven budget):
//  A: minmax partials: 128 x 22  (mapped-uint min[10], max[10], cm, cf)
//  B: hist partials:   128 x 200 at offset 2816
//  C: main partials:   3 x 1536  at offset 28416
#define WS_A 0
#define WS_B 2816
#define WS_C 28416
#define MAIN_BLOCKS 1536      // 6 blocks/CU resident
#define N_WAVES (MAIN_BLOCKS * 4)   // 6144 wave streams
#define TILE_ROWS 8
#define N_TILES 32768         // 262144 / 8
#define TILE_F4 198           // 8*99/4 float4 per array per tile

__device__ __forceinline__ unsigned int map_f(float x) {
  unsigned int b = __float_as_uint(x);
  return (b & 0x80000000u) ? ~b : (b | 0x80000000u);
}
__device__ __forceinline__ float unmap_f(unsigned int u) {
  unsigned int b = (u & 0x80000000u) ? (u ^ 0x80000000u) : ~u;
  return __uint_as_float(b);
}

// ---------------- pass 1 over data_encoded (verbatim round-0) ----------------
__global__ __launch_bounds__(256) void k_minmax(const float* __restrict__ enc,
                                                unsigned int* __restrict__ ws) {
  int tid = threadIdx.x, bid = blockIdx.x;
  const float4* e4 = (const float4*)enc;
  float mn[10], mx[10];
  #pragma unroll
  for (int j = 0; j < 10; j++) { mn[j] = 1e30f; mx[j] = -1e30f; }
  unsigned int cm = 0, cf = 0;
  #pragma unroll
  for (int i = 0; i < 8; i++) {
    size_t g = (size_t)bid * 2048 + i * 256 + tid;
    float4 a = e4[g * 3 + 0], b = e4[g * 3 + 1], c = e4[g * 3 + 2];
    float v[12] = {a.x,a.y,a.z,a.w,b.x,b.y,b.z,b.w,c.x,c.y,c.z,c.w};
    #pragma unroll
    for (int j = 0; j < 10; j++) { mn[j] = fminf(mn[j], v[j]); mx[j] = fmaxf(mx[j], v[j]); }
    cm += (v[11] == 0.0f); cf += (v[11] == 1.0f);
  }
  #pragma unroll
  for (int off = 32; off; off >>= 1) {
    #pragma unroll
    for (int j = 0; j < 10; j++) {
      mn[j] = fminf(mn[j], __shfl_xor(mn[j], off));
      mx[j] = fmaxf(mx[j], __shfl_xor(mx[j], off));
    }
    cm += __shfl_xor(cm, off); cf += __shfl_xor(cf, off);
  }
  __shared__ float smn[4][10], smx[4][10];
  __shared__ unsigned int sc[4][2];
  int wave = tid >> 6, lane = tid & 63;
  if (lane == 0) {
    #pragma unroll
    for (int j = 0; j < 10; j++) { smn[wave][j] = mn[j]; smx[wave][j] = mx[j]; }
    sc[wave][0] = cm; sc[wave][1] = cf;
  }
  __syncthreads();
  unsigned int* out = ws + WS_A + bid * 22;
  if (tid < 10) {
    float m = fminf(fminf(smn[0][tid], smn[1][tid]), fminf(smn[2][tid], smn[3][tid]));
    out[tid] = map_f(m);
  } else if (tid < 20) {
    int j = tid - 10;
    float m = fmaxf(fmaxf(smx[0][j], smx[1][j]), fmaxf(smx[2][j], smx[3][j]));
    out[tid] = map_f(m);
  } else if (tid < 22) {
    int j = tid - 20;
    out[tid] = sc[0][j] + sc[1][j] + sc[2][j] + sc[3][j];
  }
}

// ---------------- pass 2 over data_encoded: histograms (verbatim round-0) ----
__global__ __launch_bounds__(256) void k_hist(const float* __restrict__ enc,
                                              unsigned int* __restrict__ ws) {
  __shared__ float mnv[10], wid[10];
  __shared__ unsigned int h[200];
  int tid = threadIdx.x, bid = blockIdx.x;
  for (int i = tid; i < 200; i += 256) h[i] = 0u;
  if (tid < 10) {
    unsigned int umn = 0xFFFFFFFFu, umx = 0u;
    #pragma unroll 4
    for (int b = 0; b < 128; b++) {
      umn = min(umn, ws[WS_A + b * 22 + tid]);
      umx = max(umx, ws[WS_A + b * 22 + 10 + tid]);
    }
    float mn = unmap_f(umn);
    mnv[tid] = mn;
    wid[tid] = fmaxf(unmap_f(umx) - mn, 1e-12f);
  }
  __syncthreads();
  const float4* e4 = (const float4*)enc;
  #pragma unroll
  for (int i = 0; i < 8; i++) {
    size_t g = (size_t)bid * 2048 + i * 256 + tid;
    float4 a = e4[g * 3 + 0], b = e4[g * 3 + 1], c = e4[g * 3 + 2];
    float v[12] = {a.x,a.y,a.z,a.w,b.x,b.y,b.z,b.w,c.x,c.y,c.z,c.w};
    int base = (v[11] == 0.0f) ? 0 : ((v[11] == 1.0f) ? 100 : -1);
    if (base >= 0) {
      #pragma unroll
      for (int cc = 0; cc < 10; cc++) {
        float t = (v[cc] - mnv[cc]) / wid[cc] * 10.0f;  // reference op order
        int bi = min(max((int)floorf(t), 0), 9);
        atomicAdd(&h[base + cc * 10 + bi], 1u);
      }
    }
  }
  __syncthreads();
  if (tid < 200) ws[WS_B + bid * 200 + tid] = h[tid];
}

// ---------------- main pass: register staging, no DMA ----------------
// Single-variable change vs round-0: d comes through REGISTERS (m13's proven
// 6.3 TB/s path) instead of global_load_lds; the LSE consumes exp(d) placed
// in LDS via ds_write_b128 (on-chip, not a vmem op). No inline-asm waits, no
// cross-iteration register carries, no swizzle -- compiler schedules freely.
__global__ __launch_bounds__(256, 6) void k_main(const float* __restrict__ d,
                                                 const float* __restrict__ t,
                                                 unsigned int* __restrict__ ws) {
  __shared__ float sd[4][800];          // per-wave exp(d) tile (12.8 KB)
  __shared__ float red[12];
  int tid = threadIdx.x, bid = blockIdx.x;
  int wave = tid >> 6, lane = tid & 63;
  float* ldsd = sd[wave];
  float4* lw4 = (float4*)ldsd;
  int gw = bid * 4 + wave;              // global wave stream id

  float mse = 0.f, dot = 0.f, ce = 0.f;

  for (int tile = gw; tile < N_TILES; tile += N_WAVES) {
    const float4* ds = (const float4*)d + (size_t)tile * TILE_F4;
    const float4* ts = (const float4*)t + (size_t)tile * TILE_F4;
    int cl = (lane < 6) ? lane : 0;     // clamped tail index (garbage unused)
    // ---- 8 independent coalesced reg loads; compiler bursts then waits ----
    float4 d0 = ds[lane],       t0 = ts[lane];
    float4 d1 = ds[64 + lane],  t1 = ts[64 + lane];
    float4 d2 = ds[128 + lane], t2 = ts[128 + lane];
    float4 d3 = ds[192 + cl],   t3 = ts[192 + cl];
    // ---- mse/dot + all-64-lane exp in regs; exp tile -> LDS ----
    float4 dv4[4] = {d0, d1, d2, d3};
    float4 tv4[4] = {t0, t1, t2, t3};
    #pragma unroll
    for (int it = 0; it < 4; ++it) {
      if (it < 3 || lane < 6) {         // skip clamped-duplicate tail lanes
        int f = it * 64 + lane;
        float4 xd = dv4[it];
        float4 xt = tv4[it];
        int e = f * 4;
        int c = e - (e / 99) * 99;      // magic-mul const divisor
        float dv[4] = {xd.x, xd.y, xd.z, xd.w};
        float tw[4] = {xt.x, xt.y, xt.z, xt.w};
        #pragma unroll
        for (int k = 0; k < 4; k++) {
          int cc = c + k;
          if (cc >= 99) cc -= 99;
          bool cont = (cc == 0) | ((unsigned)(cc - 55) <= 2u);
          float diff = dv[k] - tw[k];
          if (cont) mse += diff * diff;
          else      dot += tw[k] * dv[k];
        }
        float4 ev;                       // vectorized exp: 64 lanes busy
        ev.x = __expf(xd.x); ev.y = __expf(xd.y);
        ev.z = __expf(xd.z); ev.w = __expf(xd.w);
        lw4[f] = ev;                     // ds_write_b128, wave-private slice
      }
    }
    // ---- LSE over exp tile: 2 lanes/row, adds + 8 logs (r5-validated) ----
    // (compiler orders ds_write -> ds_read via lgkmcnt on the same buffer)
    if (lane < 2 * TILE_ROWS) {
      const float* row = ldsd + (lane >> 1) * 99;
      float Z;
      if ((lane & 1) == 0) {            // blocks (1,8)(8,24)(24,31)(31,45)(45,51)
        Z = 0.f;
        #pragma unroll
        for (int c = 1; c < 8; c++) Z += row[c];
        ce += __logf(Z);
        Z = 0.f;
        #pragma unroll
        for (int c = 8; c < 24; c++) Z += row[c];
        ce += __logf(Z);
        Z = 0.f;
        #pragma unroll
        for (int c = 24; c < 31; c++) Z += row[c];
        ce += __logf(Z);
        Z = 0.f;
        #pragma unroll
        for (int c = 31; c < 45; c++) Z += row[c];
        ce += __logf(Z);
        Z = 0.f;
        #pragma unroll
        for (int c = 45; c < 51; c++) Z += row[c];
        ce += __logf(Z);
      } else {                          // blocks (51,53)(53,55)(58,99)
        Z = 0.f;
        #pragma unroll
        for (int c = 51; c < 53; c++) Z += row[c];
        ce += __logf(Z);
        Z = 0.f;
        #pragma unroll
        for (int c = 53; c < 55; c++) Z += row[c];
        ce += __logf(Z);
        float Za = 0.f, Zb = 0.f;       // split 41-chain into 2 accumulators
        #pragma unroll
        for (int c = 58; c < 78; c++) Za += row[c];
        #pragma unroll
        for (int c = 78; c < 99; c++) Zb += row[c];
        ce += __logf(Za + Zb);
      }
    }
  }

  // ---- block reduction (single barrier AFTER the streaming loop) ----
  #pragma unroll
  for (int off = 32; off; off >>= 1) {
    mse += __shfl_xor(mse, off);
    dot += __shfl_xor(dot, off);
    ce  += __shfl_xor(ce,  off);
  }
  if (lane == 0) { red[wave] = mse; red[4 + wave] = dot; red[8 + wave] = ce; }
  __syncthreads();
  if (tid == 0) {
    float* C = (float*)(ws + WS_C);
    C[bid]                   = red[0] + red[1] + red[2]  + red[3];
    C[MAIN_BLOCKS + bid]     = red[4] + red[5] + red[6]  + red[7];
    C[2 * MAIN_BLOCKS + bid] = red[8] + red[9] + red[10] + red[11];
  }
}

// ---------------- finalize (verbatim round-0) ----------------
__global__ __launch_bounds__(256) void k_final(const unsigned int* __restrict__ ws,
                                               float* __restrict__ out) {
  __shared__ float h[200];
  __shared__ float part[256];
  __shared__ float red3[12];
  __shared__ float cnts[2];
  int tid = threadIdx.x;
  if (tid < 200) {
    unsigned int s = 0;
    #pragma unroll 4
    for (int b = 0; b < 128; b++) s += ws[WS_B + b * 200 + tid];
    h[tid] = (float)s;
  }
  if (tid == 200 || tid == 201) {
    unsigned int s = 0;
    #pragma unroll 4
    for (int b = 0; b < 128; b++) s += ws[WS_A + b * 22 + 20 + (tid - 200)];
    cnts[tid - 200] = fmaxf((float)s, 1.0f);
  }
  const float* C = (const float*)(ws + WS_C);
  float msum = 0.f, dsum = 0.f, csum = 0.f;
  for (int i = tid; i < MAIN_BLOCKS; i += 256) {
    msum += C[i]; dsum += C[MAIN_BLOCKS + i]; csum += C[2 * MAIN_BLOCKS + i];
  }
  #pragma unroll
  for (int off = 32; off; off >>= 1) {
    msum += __shfl_xor(msum, off);
    dsum += __shfl_xor(dsum, off);
    csum += __shfl_xor(csum, off);
  }
  int wave = tid >> 6, lane = tid & 63;
  if (lane == 0) { red3[wave] = msum; red3[4 + wave] = dsum; red3[8 + wave] = csum; }
  __syncthreads();
  float term = 0.f;
  if (tid < 100) {
    float mc = h[tid], fc = h[100 + tid];
    if (mc > 0.f && fc > 0.f) {
      float p = mc / cnts[0];
      float q = fc / cnts[1];
      term = p * logf(p / q);
    }
  }
  part[tid] = term;
  __syncthreads();
  for (int s = 128; s; s >>= 1) {
    if (tid < s) part[tid] += part[tid + s];
    __syncthreads();
  }
  if (tid == 0) {
    const float invB = 1.0f / (float)B_ROWS;
    float mse = (red3[0] + red3[1] + red3[2] + red3[3]) * invB;
    float dd  = (red3[4] + red3[5] + red3[6] + red3[7]);
    float cc  = (red3[8] + red3[9] + red3[10] + red3[11]);
    float ce  = (cc - dd) * invB;
    float akld = 0.5f * part[0];
    out[0] = 0.5f * (mse + ce) + akld;
    out[1] = mse;
    out[2] = ce;
    out[3] = akld;
  }
}

extern "C" void kernel_launch(void* const* d_in, const int* in_sizes, int n_in,
                              void* d_out, int out_size, void* d_ws, size_t ws_size,
                              hipStream_t stream) {
  const float* enc = (const float*)d_in[0];   // data_encoded (B,12)
  const float* dec = (const float*)d_in[1];   // data_decoded (B,99)
  const float* tru = (const float*)d_in[2];   // data_true    (B,99)
  unsigned int* ws = (unsigned int*)d_ws;
  float* out = (float*)d_out;

  hipLaunchKernelGGL(k_minmax, dim3(128),         dim3(256), 0, stream, enc, ws);
  hipLaunchKernelGGL(k_hist,   dim3(128),         dim3(256), 0, stream, enc, ws);
  hipLaunchKernelGGL(k_main,   dim3(MAIN_BLOCKS), dim3(256), 0, stream, dec, tru, ws);
  hipLaunchKernelGGL(k_final,  dim3(1),           dim3(256), 0, stream, ws, out);
}